// Round 2
// baseline (1018.368 us; speedup 1.0000x reference)
//
#include <hip/hip_runtime.h>

#define HH 128

typedef __attribute__((ext_vector_type(8))) short bf16x8;
typedef __attribute__((ext_vector_type(4))) float f32x4;

__device__ __forceinline__ unsigned short f2bf(float f){
  unsigned int u = __builtin_bit_cast(unsigned int, f);
  u += 0x7FFFu + ((u >> 16) & 1u);        // round-to-nearest-even
  return (unsigned short)(u >> 16);
}
__device__ __forceinline__ float silu_f(float x){
  return x / (1.f + __expf(-x));
}
__device__ __forceinline__ bf16x8 pack8(const float* p){
  float4 u0 = *(const float4*)(p);
  float4 u1 = *(const float4*)(p + 4);
  bf16x8 t;
  t[0]=(short)f2bf(u0.x); t[1]=(short)f2bf(u0.y); t[2]=(short)f2bf(u0.z); t[3]=(short)f2bf(u0.w);
  t[4]=(short)f2bf(u1.x); t[5]=(short)f2bf(u1.y); t[6]=(short)f2bf(u1.z); t[7]=(short)f2bf(u1.w);
  return t;
}

// ---------------- utility ----------------
__global__ void zero_kernel(int* __restrict__ p, int n){
  int i = blockIdx.x*256 + threadIdx.x;
  if (i < n) p[i] = 0;
}

// ---------------- CSR build ----------------
__global__ void hist_kernel(const int* __restrict__ row, int* __restrict__ deg, int E){
  int e = blockIdx.x*256 + threadIdx.x;
  if (e < E) atomicAdd(&deg[row[e]], 1);
}

__global__ void scan_kernel(const int* __restrict__ deg, int* __restrict__ rowstart,
                            int* __restrict__ cursor, int N){
  __shared__ int part[1024];
  int t = threadIdx.x;
  int chunk = (N + 1023) >> 10;
  int base = t * chunk;
  int s = 0;
  for (int j = 0; j < chunk; ++j){ int i = base + j; if (i < N) s += deg[i]; }
  part[t] = s;
  __syncthreads();
  for (int off = 1; off < 1024; off <<= 1){
    int v = (t >= off) ? part[t - off] : 0;
    __syncthreads();
    part[t] += v;
    __syncthreads();
  }
  int run = part[t] - s;   // exclusive prefix
  for (int j = 0; j < chunk; ++j){
    int i = base + j;
    if (i < N){ rowstart[i] = run; cursor[i] = run; run += deg[i]; }
  }
  if (t == 1023) rowstart[N] = part[1023];
}

__global__ void scatter_kernel(const int* __restrict__ row, int* __restrict__ cursor,
                               int* __restrict__ csr, int* __restrict__ destp, int E){
  int e = blockIdx.x*256 + threadIdx.x;
  if (e < E){
    int r = row[e];
    int p = atomicAdd(&cursor[r], 1);
    csr[p] = e;
    destp[p] = r;
  }
}

// ---------------- fused edge MLPs + aggregation ----------------
// Per block: grid-stride over 16-atom chunks (CSR-contiguous edge ranges).
// pass 0: msg MLP -> accS (scalar aggregate).  pass 1: vec MLP -> accV
// (vec aggregate, vw*(dir_k + force[col,k,:])).  Chunks own their atoms
// exclusively -> plain global stores, deterministic up to LDS-atomic fp order.
// MFMA 16x16x32 bf16; A row = lane&15, k = (lane>>4)*8+j;
// C/D: col = lane&15, row = (lane>>4)*4 + reg  (guide m89-verified).
__global__ __launch_bounds__(512, 2) void fused_edge_kernel(
    const float* __restrict__ atom, const float* __restrict__ force,
    const float* __restrict__ dir,  const float* __restrict__ dist,
    const int* __restrict__ colidx,
    const int* __restrict__ rowstart, const int* __restrict__ csr,
    const int* __restrict__ destp,
    const float* __restrict__ Wm1, const float* __restrict__ bm1,
    const float* __restrict__ Wm2, const float* __restrict__ bm2,
    const float* __restrict__ Wv1, const float* __restrict__ bv1,
    const float* __restrict__ Wv2, const float* __restrict__ bv2,
    float* __restrict__ scalar_agg, float* __restrict__ vec_agg,
    int N, int nchunks)
{
  __shared__ __align__(16) unsigned short sW1[128*168];   // W1^T [col][k], pad 160->168
  __shared__ __align__(16) unsigned short sW2[128*136];   // W2^T [col][k], pad 128->136
  __shared__ __align__(16) unsigned short hbuf[8*16*136]; // per-wave transpose buffers
  __shared__ float accS[16*HH];
  __shared__ float accV[16*3*HH];

  const int tid = threadIdx.x;
  const int w = tid >> 6, lane = tid & 63;
  const int l15 = lane & 15, lg = lane >> 4;
  unsigned short* hb = &hbuf[w*16*136];

  #pragma unroll 1
  for (int pass = 0; pass < 2; ++pass){
    const float* W1 = pass ? Wv1 : Wm1;
    const float* W2 = pass ? Wv2 : Wm2;
    const float* B1 = pass ? bv1 : bm1;
    const float* B2 = pass ? bv2 : bm2;
    __syncthreads();
    for (int idx = tid; idx < 160*128; idx += 512){
      int k = idx >> 7, c = idx & 127;
      sW1[c*168 + k] = f2bf(W1[idx]);
    }
    for (int idx = tid; idx < 128*128; idx += 512){
      int k = idx >> 7, c = idx & 127;
      sW2[c*136 + k] = f2bf(W2[idx]);
    }
    __syncthreads();
    float bb1[8], bb2[8];
    #pragma unroll
    for (int n = 0; n < 8; ++n){ bb1[n] = B1[n*16 + l15]; bb2[n] = B2[n*16 + l15]; }

    for (int chunk = blockIdx.x; chunk < nchunks; chunk += gridDim.x){
      const int i0 = chunk << 4;
      const int i1 = (i0 + 16 < N) ? (i0 + 16) : N;
      const int p0 = rowstart[i0];
      const int pend = rowstart[i1];
      const int cnt = pend - p0;
      if (pass == 0){ for (int idx = tid; idx < 16*HH; idx += 512)   accS[idx] = 0.f; }
      else          { for (int idx = tid; idx < 16*3*HH; idx += 512) accV[idx] = 0.f; }
      __syncthreads();

      const int ntile = (cnt + 127) >> 7;
      for (int t = 0; t < ntile; ++t){
        const int tb = p0 + (t << 7) + (w << 4);
        // ---- A fragments: rows = 16 CSR positions of this wave ----
        int pa = tb + l15;
        if (pa >= pend) pa = pend - 1;
        const int eidA = csr[pa];
        const int ca = colidx[eidA];
        bf16x8 a[5];
        {
          const float* ar = atom + (size_t)ca*HH + lg*8;
          #pragma unroll
          for (int kt = 0; kt < 4; ++kt) a[kt] = pack8(ar + kt*32);
          a[4] = pack8(dist + (size_t)eidA*32 + lg*8);
        }
        // ---- layer 1 ----
        f32x4 acc[8];
        #pragma unroll
        for (int n = 0; n < 8; ++n){ f32x4 tt = {bb1[n],bb1[n],bb1[n],bb1[n]}; acc[n] = tt; }
        #pragma unroll
        for (int kt = 0; kt < 5; ++kt){
          #pragma unroll
          for (int n = 0; n < 8; ++n){
            bf16x8 bf = *(const bf16x8*)&sW1[(n*16 + l15)*168 + kt*32 + lg*8];
            acc[n] = __builtin_amdgcn_mfma_f32_16x16x32_bf16(a[kt], bf, acc[n], 0, 0, 0);
          }
        }
        // ---- silu + transpose through per-wave LDS ----
        #pragma unroll
        for (int n = 0; n < 8; ++n)
          #pragma unroll
          for (int j = 0; j < 4; ++j)
            hb[((lg<<2) + j)*136 + n*16 + l15] = f2bf(silu_f(acc[n][j]));
        // ---- layer 2 ----
        f32x4 acc2[8];
        #pragma unroll
        for (int n = 0; n < 8; ++n){ f32x4 tt = {bb2[n],bb2[n],bb2[n],bb2[n]}; acc2[n] = tt; }
        #pragma unroll
        for (int kt = 0; kt < 4; ++kt){
          bf16x8 a2 = *(const bf16x8*)&hb[l15*136 + kt*32 + lg*8];
          #pragma unroll
          for (int n = 0; n < 8; ++n){
            bf16x8 bf = *(const bf16x8*)&sW2[(n*16 + l15)*136 + kt*32 + lg*8];
            acc2[n] = __builtin_amdgcn_mfma_f32_16x16x32_bf16(a2, bf, acc2[n], 0, 0, 0);
          }
        }
        // ---- aggregation into LDS (CSR rows are dest-sorted -> run-merge) ----
        const int pr = tb + (lg << 2);
        int dj[4];
        #pragma unroll
        for (int j = 0; j < 4; ++j){
          int p = pr + j;
          dj[j] = (p < pend) ? (destp[p] - i0) : -1;
        }
        if (pass == 0){
          #pragma unroll
          for (int n = 0; n < 8; ++n){
            const int h = n*16 + l15;
            int drun = -1; float vrun = 0.f;
            #pragma unroll
            for (int j = 0; j < 4; ++j){
              if (dj[j] == drun){ vrun += acc2[n][j]; }
              else {
                if (drun >= 0) atomicAdd(&accS[drun*HH + h], vrun);
                drun = dj[j]; vrun = acc2[n][j];
              }
            }
            if (drun >= 0) atomicAdd(&accS[drun*HH + h], vrun);
          }
        } else {
          float dx[4], dy[4], dz[4]; int cc[4];
          #pragma unroll
          for (int j = 0; j < 4; ++j){
            if (dj[j] >= 0){
              int eid = csr[pr + j];
              cc[j] = colidx[eid];
              const float* dp = dir + (size_t)eid*3;
              dx[j] = dp[0]; dy[j] = dp[1]; dz[j] = dp[2];
            } else { cc[j] = 0; dx[j] = dy[j] = dz[j] = 0.f; }
          }
          #pragma unroll
          for (int n = 0; n < 8; ++n){
            const int h = n*16 + l15;
            int drun = -1; float s0 = 0.f, s1 = 0.f, s2 = 0.f;
            #pragma unroll
            for (int j = 0; j < 4; ++j){
              if (dj[j] != drun){
                if (drun >= 0){
                  atomicAdd(&accV[(drun*3 + 0)*HH + h], s0);
                  atomicAdd(&accV[(drun*3 + 1)*HH + h], s1);
                  atomicAdd(&accV[(drun*3 + 2)*HH + h], s2);
                }
                drun = dj[j]; s0 = s1 = s2 = 0.f;
              }
              if (dj[j] >= 0){
                float vw = acc2[n][j];
                const float* fb = force + (size_t)cc[j]*3*HH + h;
                s0 += vw*(dx[j] + fb[0]);
                s1 += vw*(dy[j] + fb[HH]);
                s2 += vw*(dz[j] + fb[2*HH]);
              }
            }
            if (drun >= 0){
              atomicAdd(&accV[(drun*3 + 0)*HH + h], s0);
              atomicAdd(&accV[(drun*3 + 1)*HH + h], s1);
              atomicAdd(&accV[(drun*3 + 2)*HH + h], s2);
            }
          }
        }
      }
      __syncthreads();
      // ---- write chunk aggregates (exclusive ownership, plain stores) ----
      if (pass == 0){
        const int tot = (i1 - i0)*HH;
        for (int idx = tid; idx < tot; idx += 512)
          scalar_agg[(size_t)i0*HH + idx] = accS[idx];
      } else {
        const int tot = (i1 - i0)*3*HH;
        for (int idx = tid; idx < tot; idx += 512)
          vec_agg[(size_t)i0*3*HH + idx] = accV[idx];
      }
      __syncthreads();
    }
  }
}

// ---------------- node / force MLP (256 -> 128 silu -> 128), bf16 MFMA ----------------
// IS_FORCE=false: X1 = scalar_agg (aliases out0), adds vec_invariant on the fly,
//                 out = atom + y  (writes out0; same-wave row read->write, safe).
// IS_FORCE=true:  X1 = vec_agg (aliases out1), out = f + y*f (writes out1).
template<bool IS_FORCE>
__global__ __launch_bounds__(512, 2) void node_mlp_kernel(
    const float* __restrict__ X0,   // atom_node (N,128)
    const float* __restrict__ X1,
    const float* __restrict__ FRC,  // force flat (N,3,128)
    const float* __restrict__ W1, const float* __restrict__ b1,
    const float* __restrict__ W2, const float* __restrict__ b2,
    float* __restrict__ out, int M)
{
  __shared__ __align__(16) unsigned short sW1[128*264];   // [col][k], pad 256->264
  __shared__ __align__(16) unsigned short sW2[128*136];
  __shared__ __align__(16) unsigned short hbuf[8*16*136];

  const int tid = threadIdx.x;
  for (int idx = tid; idx < 256*128; idx += 512){
    int k = idx >> 7, c = idx & 127;
    sW1[c*264 + k] = f2bf(W1[idx]);
  }
  for (int idx = tid; idx < 128*128; idx += 512){
    int k = idx >> 7, c = idx & 127;
    sW2[c*136 + k] = f2bf(W2[idx]);
  }
  __syncthreads();

  const int w = tid >> 6, lane = tid & 63;
  const int l15 = lane & 15, lg = lane >> 4;
  unsigned short* hb = &hbuf[w*16*136];

  float b1v[8], b2v[8];
  #pragma unroll
  for (int n = 0; n < 8; ++n){ b1v[n] = b1[n*16 + l15]; b2v[n] = b2[n*16 + l15]; }

  const int ntiles = (M + 127) >> 7;
  for (int tile = blockIdx.x; tile < ntiles; tile += gridDim.x){
    const int m0 = (tile << 7) + (w << 4);
    int r = m0 + l15;
    int rr = (r < M) ? r : (M - 1);

    bf16x8 a[8];
    {
      const float* x0 = X0 + (size_t)(IS_FORCE ? (rr/3) : rr) * HH + lg*8;
      #pragma unroll
      for (int kt = 0; kt < 4; ++kt) a[kt] = pack8(x0 + kt*32);
    }
    if (IS_FORCE){
      const float* x1 = X1 + (size_t)rr * HH + lg*8;
      #pragma unroll
      for (int kt = 0; kt < 4; ++kt) a[kt+4] = pack8(x1 + kt*32);
    } else {
      #pragma unroll
      for (int kt = 0; kt < 4; ++kt){
        const float* sp = X1  + (size_t)rr*HH   + kt*32 + lg*8;
        const float* fp = FRC + (size_t)rr*3*HH + kt*32 + lg*8;
        bf16x8 tv;
        #pragma unroll
        for (int q = 0; q < 8; ++q){
          float f0 = fp[q], f1 = fp[q + HH], f2 = fp[q + 2*HH];
          tv[q] = (short)f2bf(sp[q] + f0*f0 + f1*f1 + f2*f2);
        }
        a[kt+4] = tv;
      }
    }

    f32x4 acc[8];
    #pragma unroll
    for (int n = 0; n < 8; ++n){ f32x4 t = {b1v[n],b1v[n],b1v[n],b1v[n]}; acc[n] = t; }
    #pragma unroll
    for (int kt = 0; kt < 8; ++kt){
      #pragma unroll
      for (int n = 0; n < 8; ++n){
        bf16x8 bf = *(const bf16x8*)&sW1[(n*16 + l15)*264 + kt*32 + lg*8];
        acc[n] = __builtin_amdgcn_mfma_f32_16x16x32_bf16(a[kt], bf, acc[n], 0, 0, 0);
      }
    }

    #pragma unroll
    for (int n = 0; n < 8; ++n)
      #pragma unroll
      for (int j = 0; j < 4; ++j)
        hb[((lg<<2) + j)*136 + n*16 + l15] = f2bf(silu_f(acc[n][j]));

    f32x4 acc2[8];
    #pragma unroll
    for (int n = 0; n < 8; ++n){ f32x4 t = {b2v[n],b2v[n],b2v[n],b2v[n]}; acc2[n] = t; }
    #pragma unroll
    for (int kt = 0; kt < 4; ++kt){
      bf16x8 a2 = *(const bf16x8*)&hb[l15*136 + kt*32 + lg*8];
      #pragma unroll
      for (int n = 0; n < 8; ++n){
        bf16x8 bf = *(const bf16x8*)&sW2[(n*16 + l15)*136 + kt*32 + lg*8];
        acc2[n] = __builtin_amdgcn_mfma_f32_16x16x32_bf16(a2, bf, acc2[n], 0, 0, 0);
      }
    }

    // epilogue: scattered f32 stores (64B-contiguous per 16-lane group)
    #pragma unroll
    for (int n = 0; n < 8; ++n){
      #pragma unroll
      for (int j = 0; j < 4; ++j){
        int R = m0 + (lg<<2) + j;
        if (R < M){
          size_t o = (size_t)R*HH + n*16 + l15;
          float y = acc2[n][j];
          float res;
          if (IS_FORCE){ float f = FRC[o]; res = f + y*f; }
          else         { res = X0[o] + y; }
          out[o] = res;
        }
      }
    }
  }
}

// ---------------- launch ----------------
extern "C" void kernel_launch(void* const* d_in, const int* in_sizes, int n_in,
                              void* d_out, int out_size, void* d_ws, size_t ws_size,
                              hipStream_t stream)
{
  const float* atom  = (const float*)d_in[0];
  const float* force = (const float*)d_in[1];
  const float* dir   = (const float*)d_in[2];
  const float* dist  = (const float*)d_in[3];
  const int*   eidx  = (const int*)d_in[4];
  const float* Wm1 = (const float*)d_in[5];  const float* bm1 = (const float*)d_in[6];
  const float* Wm2 = (const float*)d_in[7];  const float* bm2 = (const float*)d_in[8];
  const float* Wv1 = (const float*)d_in[9];  const float* bv1 = (const float*)d_in[10];
  const float* Wv2 = (const float*)d_in[11]; const float* bv2 = (const float*)d_in[12];
  const float* Wn1 = (const float*)d_in[13]; const float* bn1 = (const float*)d_in[14];
  const float* Wn2 = (const float*)d_in[15]; const float* bn2 = (const float*)d_in[16];
  const float* Wf1 = (const float*)d_in[17]; const float* bf1 = (const float*)d_in[18];
  const float* Wf2 = (const float*)d_in[19]; const float* bf2 = (const float*)d_in[20];

  const int N = in_sizes[0] / HH;
  const int E = in_sizes[2] / 3;
  const int* rowi = eidx;
  const int* coli = eidx + E;

  // workspace: CSR only (~5.3 MB)
  char* ws = (char*)d_ws;
  size_t off = 0;
  auto take = [&](size_t bytes) -> void* {
    void* p = (void*)(ws + off);
    off += (bytes + 255) & ~(size_t)255;
    return p;
  };
  int* deg      = (int*)take((size_t)(N+1)*4);
  int* rowstart = (int*)take((size_t)(N+1)*4);
  int* cursor   = (int*)take((size_t)N*4);
  int* csr      = (int*)take((size_t)E*4);
  int* destp    = (int*)take((size_t)E*4);
  if (off > ws_size) return;  // degrade to wrong answer, not a page fault
  (void)n_in; (void)out_size;

  // aggregates alias d_out (fully overwritten by the MLP kernels afterwards)
  float* out0 = (float*)d_out;                    // scalar_agg -> atom_node_new
  float* out1 = out0 + (size_t)N*HH;              // vec_agg   -> force_node_new

  zero_kernel<<<(N+256)/256, 256, 0, stream>>>(deg, N+1);
  hist_kernel<<<(E+255)/256, 256, 0, stream>>>(rowi, deg, E);
  scan_kernel<<<1, 1024, 0, stream>>>(deg, rowstart, cursor, N);
  scatter_kernel<<<(E+255)/256, 256, 0, stream>>>(rowi, cursor, csr, destp, E);

  const int nchunks = (N + 15) >> 4;
  int fgrid = nchunks < 256 ? nchunks : 256;
  fused_edge_kernel<<<fgrid, 512, 0, stream>>>(atom, force, dir, dist, coli,
      rowstart, csr, destp,
      Wm1,bm1,Wm2,bm2, Wv1,bv1,Wv2,bv2,
      out0, out1, N, nchunks);

  int nt_node  = (N + 127) >> 7;
  int nt_force = (3*N + 127) >> 7;
  node_mlp_kernel<false><<<nt_node, 512, 0, stream>>>(atom, out0, force,
      Wn1,bn1,Wn2,bn2, out0, N);
  node_mlp_kernel<true><<<nt_force, 512, 0, stream>>>(atom, out1, force,
      Wf1,bf1,Wf2,bf2, out1, 3*N);
}

// Round 3
// 1016.869 us; speedup vs baseline: 1.0015x; 1.0015x over previous
//
#include <hip/hip_runtime.h>

#define HH 128

typedef __attribute__((ext_vector_type(8))) short bf16x8;
typedef __attribute__((ext_vector_type(4))) float f32x4;

__device__ __forceinline__ unsigned short f2bf(float f){
  unsigned int u = __builtin_bit_cast(unsigned int, f);
  u += 0x7FFFu + ((u >> 16) & 1u);        // round-to-nearest-even
  return (unsigned short)(u >> 16);
}
__device__ __forceinline__ float bf2f(unsigned int lo16){
  return __builtin_bit_cast(float, lo16 << 16);
}
__device__ __forceinline__ float silu_f(float x){
  return x / (1.f + __expf(-x));
}
__device__ __forceinline__ bf16x8 pack8(const float* p){
  float4 u0 = *(const float4*)(p);
  float4 u1 = *(const float4*)(p + 4);
  bf16x8 t;
  t[0]=(short)f2bf(u0.x); t[1]=(short)f2bf(u0.y); t[2]=(short)f2bf(u0.z); t[3]=(short)f2bf(u0.w);
  t[4]=(short)f2bf(u1.x); t[5]=(short)f2bf(u1.y); t[6]=(short)f2bf(u1.z); t[7]=(short)f2bf(u1.w);
  return t;
}

// ---------------- utility ----------------
__global__ void zero_kernel(int* __restrict__ p, int n){
  int i = blockIdx.x*256 + threadIdx.x;
  if (i < n) p[i] = 0;
}

// ---------------- CSR build ----------------
__global__ void hist_kernel(const int* __restrict__ row, int* __restrict__ deg, int E){
  int e = blockIdx.x*256 + threadIdx.x;
  if (e < E) atomicAdd(&deg[row[e]], 1);
}

__global__ void scan_kernel(const int* __restrict__ deg, int* __restrict__ rowstart,
                            int* __restrict__ cursor, int N){
  __shared__ int part[1024];
  int t = threadIdx.x;
  int chunk = (N + 1023) >> 10;
  int base = t * chunk;
  int s = 0;
  for (int j = 0; j < chunk; ++j){ int i = base + j; if (i < N) s += deg[i]; }
  part[t] = s;
  __syncthreads();
  for (int off = 1; off < 1024; off <<= 1){
    int v = (t >= off) ? part[t - off] : 0;
    __syncthreads();
    part[t] += v;
    __syncthreads();
  }
  int run = part[t] - s;   // exclusive prefix
  for (int j = 0; j < chunk; ++j){
    int i = base + j;
    if (i < N){ rowstart[i] = run; cursor[i] = run; run += deg[i]; }
  }
  if (t == 1023) rowstart[N] = part[1023];
}

__global__ void scatter_kernel(const int* __restrict__ row, int* __restrict__ cursor,
                               int* __restrict__ csr, int* __restrict__ destp, int E){
  int e = blockIdx.x*256 + threadIdx.x;
  if (e < E){
    int r = row[e];
    int p = atomicAdd(&cursor[r], 1);
    csr[p] = e;
    destp[p] = r;
  }
}

// ---------------- fused edge MLPs + aggregation ----------------
// 1024 threads (16 waves), chunk = 8 atoms (CSR-contiguous, avg 256 edges).
// pass 0: msg MLP -> scalar aggregate (per-lane register run-merge).
// pass 1: vec MLP -> vec aggregate via edge-serial wave-uniform loop:
//   vw staged in per-wave LDS, force rows loaded as coalesced float2,
//   register run-merge over dest-sorted CSR, rare LDS-atomic flushes.
// MFMA 16x16x32 bf16; A row = lane&15, k = (lane>>4)*8+j;
// C/D: col = lane&15, row = (lane>>4)*4 + reg.
__global__ __launch_bounds__(1024, 4) void fused_edge_kernel(
    const float* __restrict__ atom, const float* __restrict__ force,
    const float* __restrict__ dir,  const float* __restrict__ dist,
    const int* __restrict__ colidx,
    const int* __restrict__ rowstart, const int* __restrict__ csr,
    const int* __restrict__ destp,
    const float* __restrict__ Wm1, const float* __restrict__ bm1,
    const float* __restrict__ Wm2, const float* __restrict__ bm2,
    const float* __restrict__ Wv1, const float* __restrict__ bv1,
    const float* __restrict__ Wv2, const float* __restrict__ bv2,
    float* __restrict__ scalar_agg, float* __restrict__ vec_agg,
    int N, int nchunks)
{
  __shared__ __align__(16) unsigned short sW1[128*168];    // 43008 B
  __shared__ __align__(16) unsigned short sW2[128*136];    // 34816 B
  __shared__ __align__(16) unsigned short hbuf[16*16*136]; // 69632 B
  __shared__ float accU[8*3*HH];                           // 12288 B (pass0 uses 8*HH)

  const int tid = threadIdx.x;
  const int w = tid >> 6, lane = tid & 63;
  const int l15 = lane & 15, lg = lane >> 4;
  unsigned short* hb = &hbuf[w*16*136];

  #pragma unroll 1
  for (int pass = 0; pass < 2; ++pass){
    const float* W1 = pass ? Wv1 : Wm1;
    const float* W2 = pass ? Wv2 : Wm2;
    const float* B1 = pass ? bv1 : bm1;
    const float* B2 = pass ? bv2 : bm2;
    __syncthreads();
    for (int idx = tid; idx < 160*128; idx += 1024){
      int k = idx >> 7, c = idx & 127;
      sW1[c*168 + k] = f2bf(W1[idx]);
    }
    for (int idx = tid; idx < 128*128; idx += 1024){
      int k = idx >> 7, c = idx & 127;
      sW2[c*136 + k] = f2bf(W2[idx]);
    }
    __syncthreads();
    float bb1[8], bb2[8];
    #pragma unroll
    for (int n = 0; n < 8; ++n){ bb1[n] = B1[n*16 + l15]; bb2[n] = B2[n*16 + l15]; }

    for (int chunk = blockIdx.x; chunk < nchunks; chunk += gridDim.x){
      const int i0 = chunk << 3;
      const int i1 = (i0 + 8 < N) ? (i0 + 8) : N;
      const int p0 = rowstart[i0];
      const int pend = rowstart[i1];
      {
        const int ztot = pass ? 8*3*HH : 8*HH;
        for (int idx = tid; idx < ztot; idx += 1024) accU[idx] = 0.f;
      }
      __syncthreads();

      const int ntile = (pend - p0 + 255) >> 8;
      for (int t = 0; t < ntile; ++t){
        const int tb = p0 + (t << 8) + (w << 4);
        if (tb < pend){
          // ---- A fragments ----
          int pa = tb + l15;
          if (pa >= pend) pa = pend - 1;
          const int eidA = csr[pa];
          const int ca = colidx[eidA];
          bf16x8 a[5];
          {
            const float* ar = atom + (size_t)ca*HH + lg*8;
            #pragma unroll
            for (int kt = 0; kt < 4; ++kt) a[kt] = pack8(ar + kt*32);
            a[4] = pack8(dist + (size_t)eidA*32 + lg*8);
          }
          // ---- layer 1 ----
          f32x4 acc[8];
          #pragma unroll
          for (int n = 0; n < 8; ++n){ f32x4 tt = {bb1[n],bb1[n],bb1[n],bb1[n]}; acc[n] = tt; }
          #pragma unroll
          for (int kt = 0; kt < 5; ++kt){
            #pragma unroll
            for (int n = 0; n < 8; ++n){
              bf16x8 bf = *(const bf16x8*)&sW1[(n*16 + l15)*168 + kt*32 + lg*8];
              acc[n] = __builtin_amdgcn_mfma_f32_16x16x32_bf16(a[kt], bf, acc[n], 0, 0, 0);
            }
          }
          // ---- silu + transpose through per-wave LDS ----
          #pragma unroll
          for (int n = 0; n < 8; ++n)
            #pragma unroll
            for (int j = 0; j < 4; ++j)
              hb[((lg<<2) + j)*136 + n*16 + l15] = f2bf(silu_f(acc[n][j]));
          // ---- layer 2 ----
          f32x4 acc2[8];
          #pragma unroll
          for (int n = 0; n < 8; ++n){ f32x4 tt = {bb2[n],bb2[n],bb2[n],bb2[n]}; acc2[n] = tt; }
          #pragma unroll
          for (int kt = 0; kt < 4; ++kt){
            bf16x8 a2 = *(const bf16x8*)&hb[l15*136 + kt*32 + lg*8];
            #pragma unroll
            for (int n = 0; n < 8; ++n){
              bf16x8 bf = *(const bf16x8*)&sW2[(n*16 + l15)*136 + kt*32 + lg*8];
              acc2[n] = __builtin_amdgcn_mfma_f32_16x16x32_bf16(a2, bf, acc2[n], 0, 0, 0);
            }
          }

          if (pass == 0){
            // ---- scalar aggregation: per-lane register run-merge ----
            const int pr = tb + (lg << 2);
            int dj[4];
            #pragma unroll
            for (int j = 0; j < 4; ++j){
              int p = pr + j;
              dj[j] = (p < pend) ? (destp[p] - i0) : -1;
            }
            #pragma unroll
            for (int n = 0; n < 8; ++n){
              const int h = n*16 + l15;
              int drun = -1; float vrun = 0.f;
              #pragma unroll
              for (int j = 0; j < 4; ++j){
                if (dj[j] == drun){ vrun += acc2[n][j]; }
                else {
                  if (drun >= 0) atomicAdd(&accU[drun*HH + h], vrun);
                  drun = dj[j]; vrun = acc2[n][j];
                }
              }
              if (drun >= 0) atomicAdd(&accU[drun*HH + h], vrun);
            }
          } else {
            // ---- vec aggregation: stage vw to LDS, edge-serial wave-uniform ----
            #pragma unroll
            for (int n = 0; n < 8; ++n)
              #pragma unroll
              for (int j = 0; j < 4; ++j)
                hb[((lg<<2) + j)*136 + n*16 + l15] = f2bf(acc2[n][j]);

            int rmax = pend - tb; if (rmax > 16) rmax = 16;
            const int ch = lane << 1;
            int drun = -1;
            float v00=0.f,v01=0.f,v10=0.f,v11=0.f,v20=0.f,v21=0.f;
            for (int r = 0; r < rmax; ++r){
              const int p = tb + r;
              const int di = destp[p] - i0;           // wave-uniform
              const int eid = csr[p];                 // wave-uniform
              const int c = colidx[eid];
              const float* dp = dir + (size_t)eid*3;
              const float d0 = dp[0], d1 = dp[1], d2 = dp[2];
              const float* fb = force + (size_t)c*3*HH + ch;
              const float2 fx = *(const float2*)(fb);
              const float2 fy = *(const float2*)(fb + HH);
              const float2 fz = *(const float2*)(fb + 2*HH);
              const unsigned int vw2 = *(const unsigned int*)&hb[r*136 + ch];
              const float vl = bf2f(vw2 & 0xffffu), vh = bf2f(vw2 >> 16);
              if (di != drun){
                if (drun >= 0){
                  atomicAdd(&accU[(drun*3 + 0)*HH + ch],     v00);
                  atomicAdd(&accU[(drun*3 + 0)*HH + ch + 1], v01);
                  atomicAdd(&accU[(drun*3 + 1)*HH + ch],     v10);
                  atomicAdd(&accU[(drun*3 + 1)*HH + ch + 1], v11);
                  atomicAdd(&accU[(drun*3 + 2)*HH + ch],     v20);
                  atomicAdd(&accU[(drun*3 + 2)*HH + ch + 1], v21);
                }
                drun = di;
                v00=0.f; v01=0.f; v10=0.f; v11=0.f; v20=0.f; v21=0.f;
              }
              v00 += vl*(d0 + fx.x); v01 += vh*(d0 + fx.y);
              v10 += vl*(d1 + fy.x); v11 += vh*(d1 + fy.y);
              v20 += vl*(d2 + fz.x); v21 += vh*(d2 + fz.y);
            }
            if (drun >= 0){
              atomicAdd(&accU[(drun*3 + 0)*HH + ch],     v00);
              atomicAdd(&accU[(drun*3 + 0)*HH + ch + 1], v01);
              atomicAdd(&accU[(drun*3 + 1)*HH + ch],     v10);
              atomicAdd(&accU[(drun*3 + 1)*HH + ch + 1], v11);
              atomicAdd(&accU[(drun*3 + 2)*HH + ch],     v20);
              atomicAdd(&accU[(drun*3 + 2)*HH + ch + 1], v21);
            }
          }
        }
      }
      __syncthreads();
      // ---- write chunk aggregates (exclusive ownership, plain stores) ----
      if (pass == 0){
        const int tot = (i1 - i0)*HH;
        for (int idx = tid; idx < tot; idx += 1024)
          scalar_agg[(size_t)i0*HH + idx] = accU[idx];
      } else {
        const int tot = (i1 - i0)*3*HH;
        for (int idx = tid; idx < tot; idx += 1024)
          vec_agg[(size_t)i0*3*HH + idx] = accU[idx];
      }
      __syncthreads();
    }
  }
}

// ---------------- node / force MLP (256 -> 128 silu -> 128), bf16 MFMA ----------------
template<bool IS_FORCE>
__global__ __launch_bounds__(512, 2) void node_mlp_kernel(
    const float* __restrict__ X0,   // atom_node (N,128)
    const float* __restrict__ X1,
    const float* __restrict__ FRC,  // force flat (N,3,128)
    const float* __restrict__ W1, const float* __restrict__ b1,
    const float* __restrict__ W2, const float* __restrict__ b2,
    float* __restrict__ out, int M)
{
  __shared__ __align__(16) unsigned short sW1[128*264];   // [col][k], pad 256->264
  __shared__ __align__(16) unsigned short sW2[128*136];
  __shared__ __align__(16) unsigned short hbuf[8*16*136];

  const int tid = threadIdx.x;
  for (int idx = tid; idx < 256*128; idx += 512){
    int k = idx >> 7, c = idx & 127;
    sW1[c*264 + k] = f2bf(W1[idx]);
  }
  for (int idx = tid; idx < 128*128; idx += 512){
    int k = idx >> 7, c = idx & 127;
    sW2[c*136 + k] = f2bf(W2[idx]);
  }
  __syncthreads();

  const int w = tid >> 6, lane = tid & 63;
  const int l15 = lane & 15, lg = lane >> 4;
  unsigned short* hb = &hbuf[w*16*136];

  float b1v[8], b2v[8];
  #pragma unroll
  for (int n = 0; n < 8; ++n){ b1v[n] = b1[n*16 + l15]; b2v[n] = b2[n*16 + l15]; }

  const int ntiles = (M + 127) >> 7;
  for (int tile = blockIdx.x; tile < ntiles; tile += gridDim.x){
    const int m0 = (tile << 7) + (w << 4);
    int r = m0 + l15;
    int rr = (r < M) ? r : (M - 1);

    bf16x8 a[8];
    {
      const float* x0 = X0 + (size_t)(IS_FORCE ? (rr/3) : rr) * HH + lg*8;
      #pragma unroll
      for (int kt = 0; kt < 4; ++kt) a[kt] = pack8(x0 + kt*32);
    }
    if (IS_FORCE){
      const float* x1 = X1 + (size_t)rr * HH + lg*8;
      #pragma unroll
      for (int kt = 0; kt < 4; ++kt) a[kt+4] = pack8(x1 + kt*32);
    } else {
      #pragma unroll
      for (int kt = 0; kt < 4; ++kt){
        const float* sp = X1  + (size_t)rr*HH   + kt*32 + lg*8;
        const float* fp = FRC + (size_t)rr*3*HH + kt*32 + lg*8;
        bf16x8 tv;
        #pragma unroll
        for (int q = 0; q < 8; ++q){
          float f0 = fp[q], f1 = fp[q + HH], f2 = fp[q + 2*HH];
          tv[q] = (short)f2bf(sp[q] + f0*f0 + f1*f1 + f2*f2);
        }
        a[kt+4] = tv;
      }
    }

    f32x4 acc[8];
    #pragma unroll
    for (int n = 0; n < 8; ++n){ f32x4 t = {b1v[n],b1v[n],b1v[n],b1v[n]}; acc[n] = t; }
    #pragma unroll
    for (int kt = 0; kt < 8; ++kt){
      #pragma unroll
      for (int n = 0; n < 8; ++n){
        bf16x8 bf = *(const bf16x8*)&sW1[(n*16 + l15)*264 + kt*32 + lg*8];
        acc[n] = __builtin_amdgcn_mfma_f32_16x16x32_bf16(a[kt], bf, acc[n], 0, 0, 0);
      }
    }

    #pragma unroll
    for (int n = 0; n < 8; ++n)
      #pragma unroll
      for (int j = 0; j < 4; ++j)
        hb[((lg<<2) + j)*136 + n*16 + l15] = f2bf(silu_f(acc[n][j]));

    f32x4 acc2[8];
    #pragma unroll
    for (int n = 0; n < 8; ++n){ f32x4 t = {b2v[n],b2v[n],b2v[n],b2v[n]}; acc2[n] = t; }
    #pragma unroll
    for (int kt = 0; kt < 4; ++kt){
      bf16x8 a2 = *(const bf16x8*)&hb[l15*136 + kt*32 + lg*8];
      #pragma unroll
      for (int n = 0; n < 8; ++n){
        bf16x8 bf = *(const bf16x8*)&sW2[(n*16 + l15)*136 + kt*32 + lg*8];
        acc2[n] = __builtin_amdgcn_mfma_f32_16x16x32_bf16(a2, bf, acc2[n], 0, 0, 0);
      }
    }

    // epilogue: scattered f32 stores (64B-contiguous per 16-lane group)
    #pragma unroll
    for (int n = 0; n < 8; ++n){
      #pragma unroll
      for (int j = 0; j < 4; ++j){
        int R = m0 + (lg<<2) + j;
        if (R < M){
          size_t o = (size_t)R*HH + n*16 + l15;
          float y = acc2[n][j];
          float res;
          if (IS_FORCE){ float f = FRC[o]; res = f + y*f; }
          else         { res = X0[o] + y; }
          out[o] = res;
        }
      }
    }
  }
}

// ---------------- launch ----------------
extern "C" void kernel_launch(void* const* d_in, const int* in_sizes, int n_in,
                              void* d_out, int out_size, void* d_ws, size_t ws_size,
                              hipStream_t stream)
{
  const float* atom  = (const float*)d_in[0];
  const float* force = (const float*)d_in[1];
  const float* dir   = (const float*)d_in[2];
  const float* dist  = (const float*)d_in[3];
  const int*   eidx  = (const int*)d_in[4];
  const float* Wm1 = (const float*)d_in[5];  const float* bm1 = (const float*)d_in[6];
  const float* Wm2 = (const float*)d_in[7];  const float* bm2 = (const float*)d_in[8];
  const float* Wv1 = (const float*)d_in[9];  const float* bv1 = (const float*)d_in[10];
  const float* Wv2 = (const float*)d_in[11]; const float* bv2 = (const float*)d_in[12];
  const float* Wn1 = (const float*)d_in[13]; const float* bn1 = (const float*)d_in[14];
  const float* Wn2 = (const float*)d_in[15]; const float* bn2 = (const float*)d_in[16];
  const float* Wf1 = (const float*)d_in[17]; const float* bf1 = (const float*)d_in[18];
  const float* Wf2 = (const float*)d_in[19]; const float* bf2 = (const float*)d_in[20];

  const int N = in_sizes[0] / HH;
  const int E = in_sizes[2] / 3;
  const int* rowi = eidx;
  const int* coli = eidx + E;

  // workspace: CSR only (~5.3 MB)
  char* ws = (char*)d_ws;
  size_t off = 0;
  auto take = [&](size_t bytes) -> void* {
    void* p = (void*)(ws + off);
    off += (bytes + 255) & ~(size_t)255;
    return p;
  };
  int* deg      = (int*)take((size_t)(N+1)*4);
  int* rowstart = (int*)take((size_t)(N+1)*4);
  int* cursor   = (int*)take((size_t)N*4);
  int* csr      = (int*)take((size_t)E*4);
  int* destp    = (int*)take((size_t)E*4);
  if (off > ws_size) return;  // degrade to wrong answer, not a page fault
  (void)n_in; (void)out_size;

  // aggregates alias d_out (fully overwritten by the MLP kernels afterwards)
  float* out0 = (float*)d_out;                    // scalar_agg -> atom_node_new
  float* out1 = out0 + (size_t)N*HH;              // vec_agg   -> force_node_new

  zero_kernel<<<(N+256)/256, 256, 0, stream>>>(deg, N+1);
  hist_kernel<<<(E+255)/256, 256, 0, stream>>>(rowi, deg, E);
  scan_kernel<<<1, 1024, 0, stream>>>(deg, rowstart, cursor, N);
  scatter_kernel<<<(E+255)/256, 256, 0, stream>>>(rowi, cursor, csr, destp, E);

  const int nchunks = (N + 7) >> 3;
  int fgrid = nchunks < 256 ? nchunks : 256;
  fused_edge_kernel<<<fgrid, 1024, 0, stream>>>(atom, force, dir, dist, coli,
      rowstart, csr, destp,
      Wm1,bm1,Wm2,bm2, Wv1,bv1,Wv2,bv2,
      out0, out1, N, nchunks);

  int nt_node  = (N + 127) >> 7;
  int nt_force = (3*N + 127) >> 7;
  node_mlp_kernel<false><<<nt_node, 512, 0, stream>>>(atom, out0, force,
      Wn1,bn1,Wn2,bn2, out0, N);
  node_mlp_kernel<true><<<nt_force, 512, 0, stream>>>(atom, out1, force,
      Wf1,bf1,Wf2,bf2, out1, 3*N);
}

// Round 4
// 846.944 us; speedup vs baseline: 1.2024x; 1.2006x over previous
//
#include <hip/hip_runtime.h>

#define HH 128

typedef __attribute__((ext_vector_type(8))) short bf16x8;
typedef __attribute__((ext_vector_type(4))) float f32x4;

__device__ __forceinline__ unsigned short f2bf(float f){
  unsigned int u = __builtin_bit_cast(unsigned int, f);
  u += 0x7FFFu + ((u >> 16) & 1u);        // round-to-nearest-even
  return (unsigned short)(u >> 16);
}
__device__ __forceinline__ float bf2f(unsigned int lo16){
  return __builtin_bit_cast(float, lo16 << 16);
}
__device__ __forceinline__ float silu_f(float x){
  return x / (1.f + __expf(-x));
}
__device__ __forceinline__ bf16x8 pack8(const float* p){
  float4 u0 = *(const float4*)(p);
  float4 u1 = *(const float4*)(p + 4);
  bf16x8 t;
  t[0]=(short)f2bf(u0.x); t[1]=(short)f2bf(u0.y); t[2]=(short)f2bf(u0.z); t[3]=(short)f2bf(u0.w);
  t[4]=(short)f2bf(u1.x); t[5]=(short)f2bf(u1.y); t[6]=(short)f2bf(u1.z); t[7]=(short)f2bf(u1.w);
  return t;
}

// ---------------- utility ----------------
__global__ void zero_kernel(int* __restrict__ p, int n){
  int i = blockIdx.x*256 + threadIdx.x;
  if (i < n) p[i] = 0;
}

// f32 -> bf16 conversion, 4 elements/thread
__global__ void tobf_kernel(const float* __restrict__ in, unsigned short* __restrict__ out, int n4){
  int i = blockIdx.x*256 + threadIdx.x;
  if (i < n4){
    float4 v = *(const float4*)(in + (size_t)i*4);
    uint2 r;
    r.x = (unsigned int)f2bf(v.x) | ((unsigned int)f2bf(v.y) << 16);
    r.y = (unsigned int)f2bf(v.z) | ((unsigned int)f2bf(v.w) << 16);
    *(uint2*)(out + (size_t)i*4) = r;
  }
}

// ---------------- CSR build ----------------
__global__ void hist_kernel(const int* __restrict__ row, int* __restrict__ deg, int E){
  int e = blockIdx.x*256 + threadIdx.x;
  if (e < E) atomicAdd(&deg[row[e]], 1);
}

__global__ void scan_kernel(const int* __restrict__ deg, int* __restrict__ rowstart,
                            int* __restrict__ cursor, int N){
  __shared__ int part[1024];
  int t = threadIdx.x;
  int chunk = (N + 1023) >> 10;
  int base = t * chunk;
  int s = 0;
  for (int j = 0; j < chunk; ++j){ int i = base + j; if (i < N) s += deg[i]; }
  part[t] = s;
  __syncthreads();
  for (int off = 1; off < 1024; off <<= 1){
    int v = (t >= off) ? part[t - off] : 0;
    __syncthreads();
    part[t] += v;
    __syncthreads();
  }
  int run = part[t] - s;   // exclusive prefix
  for (int j = 0; j < chunk; ++j){
    int i = base + j;
    if (i < N){ rowstart[i] = run; cursor[i] = run; run += deg[i]; }
  }
  if (t == 1023) rowstart[N] = part[1023];
}

__global__ void scatter_kernel(const int* __restrict__ row, int* __restrict__ cursor,
                               int* __restrict__ csr, int* __restrict__ destp, int E){
  int e = blockIdx.x*256 + threadIdx.x;
  if (e < E){
    int r = row[e];
    int p = atomicAdd(&cursor[r], 1);
    csr[p] = e;
    destp[p] = r;
  }
}

// ---------------- fused edge MLPs + aggregation ----------------
// 512 threads (8 waves), chunk = 8 atoms (~256 edges), tile = 128 edges.
// pass 0: msg MLP -> scalar aggregate (per-lane register run-merge).
// pass 1: vec MLP -> vec aggregate; gather pipelined: lanes 0-15 prefetch all
//   16 edges' csr/dest/col/dir, then unrolled loop with __shfl (readlane ->
//   SGPR, wave-uniform run-merge branch), force rows gathered as bf16.
__global__ __launch_bounds__(512, 2) void fused_edge_kernel(
    const unsigned short* __restrict__ atom_bf,
    const unsigned short* __restrict__ force_bf,
    const float* __restrict__ dir,  const float* __restrict__ dist,
    const int* __restrict__ colidx,
    const int* __restrict__ rowstart, const int* __restrict__ csr,
    const int* __restrict__ destp,
    const float* __restrict__ Wm1, const float* __restrict__ bm1,
    const float* __restrict__ Wm2, const float* __restrict__ bm2,
    const float* __restrict__ Wv1, const float* __restrict__ bv1,
    const float* __restrict__ Wv2, const float* __restrict__ bv2,
    float* __restrict__ scalar_agg, float* __restrict__ vec_agg,
    int N, int nchunks)
{
  __shared__ __align__(16) unsigned short sW1[128*168];   // 43008 B
  __shared__ __align__(16) unsigned short sW2[128*136];   // 34816 B
  __shared__ __align__(16) unsigned short hbuf[8*16*136]; // 34816 B
  __shared__ float accU[8*3*HH];                          // 12288 B

  const int tid = threadIdx.x;
  const int w = tid >> 6, lane = tid & 63;
  const int l15 = lane & 15, lg = lane >> 4;
  unsigned short* hb = &hbuf[w*16*136];

  #pragma unroll 1
  for (int pass = 0; pass < 2; ++pass){
    const float* W1 = pass ? Wv1 : Wm1;
    const float* W2 = pass ? Wv2 : Wm2;
    const float* B1 = pass ? bv1 : bm1;
    const float* B2 = pass ? bv2 : bm2;
    __syncthreads();
    for (int idx = tid; idx < 160*128; idx += 512){
      int k = idx >> 7, c = idx & 127;
      sW1[c*168 + k] = f2bf(W1[idx]);
    }
    for (int idx = tid; idx < 128*128; idx += 512){
      int k = idx >> 7, c = idx & 127;
      sW2[c*136 + k] = f2bf(W2[idx]);
    }
    __syncthreads();
    float bb1[8], bb2[8];
    #pragma unroll
    for (int n = 0; n < 8; ++n){ bb1[n] = B1[n*16 + l15]; bb2[n] = B2[n*16 + l15]; }

    for (int chunk = blockIdx.x; chunk < nchunks; chunk += gridDim.x){
      const int i0 = chunk << 3;
      const int i1 = (i0 + 8 < N) ? (i0 + 8) : N;
      const int p0 = rowstart[i0];
      const int pend = rowstart[i1];
      {
        const int ztot = pass ? 8*3*HH : 8*HH;
        for (int idx = tid; idx < ztot; idx += 512) accU[idx] = 0.f;
      }
      __syncthreads();

      const int ntile = (pend - p0 + 127) >> 7;
      for (int t = 0; t < ntile; ++t){
        const int tb = p0 + (t << 7) + (w << 4);
        if (tb < pend){
          // ---- A fragments (atom rows gathered as bf16) ----
          int pa = tb + l15;
          if (pa >= pend) pa = pend - 1;
          const int eidA = csr[pa];
          const int ca = colidx[eidA];
          bf16x8 a[5];
          {
            const unsigned short* ar = atom_bf + (size_t)ca*HH + lg*8;
            #pragma unroll
            for (int kt = 0; kt < 4; ++kt) a[kt] = *(const bf16x8*)(ar + kt*32);
            a[4] = pack8(dist + (size_t)eidA*32 + lg*8);
          }
          // ---- layer 1 ----
          f32x4 acc[8];
          #pragma unroll
          for (int n = 0; n < 8; ++n){ f32x4 tt = {bb1[n],bb1[n],bb1[n],bb1[n]}; acc[n] = tt; }
          #pragma unroll
          for (int kt = 0; kt < 5; ++kt){
            #pragma unroll
            for (int n = 0; n < 8; ++n){
              bf16x8 bf = *(const bf16x8*)&sW1[(n*16 + l15)*168 + kt*32 + lg*8];
              acc[n] = __builtin_amdgcn_mfma_f32_16x16x32_bf16(a[kt], bf, acc[n], 0, 0, 0);
            }
          }
          // ---- silu + transpose through per-wave LDS ----
          #pragma unroll
          for (int n = 0; n < 8; ++n)
            #pragma unroll
            for (int j = 0; j < 4; ++j)
              hb[((lg<<2) + j)*136 + n*16 + l15] = f2bf(silu_f(acc[n][j]));
          // ---- layer 2 ----
          f32x4 acc2[8];
          #pragma unroll
          for (int n = 0; n < 8; ++n){ f32x4 tt = {bb2[n],bb2[n],bb2[n],bb2[n]}; acc2[n] = tt; }
          #pragma unroll
          for (int kt = 0; kt < 4; ++kt){
            bf16x8 a2 = *(const bf16x8*)&hb[l15*136 + kt*32 + lg*8];
            #pragma unroll
            for (int n = 0; n < 8; ++n){
              bf16x8 bf = *(const bf16x8*)&sW2[(n*16 + l15)*136 + kt*32 + lg*8];
              acc2[n] = __builtin_amdgcn_mfma_f32_16x16x32_bf16(a2, bf, acc2[n], 0, 0, 0);
            }
          }

          if (pass == 0){
            // ---- scalar aggregation: per-lane register run-merge ----
            const int pr = tb + (lg << 2);
            int dj[4];
            #pragma unroll
            for (int j = 0; j < 4; ++j){
              int p = pr + j;
              dj[j] = (p < pend) ? (destp[p] - i0) : -1;
            }
            #pragma unroll
            for (int n = 0; n < 8; ++n){
              const int h = n*16 + l15;
              int drun = -1; float vrun = 0.f;
              #pragma unroll
              for (int j = 0; j < 4; ++j){
                if (dj[j] == drun){ vrun += acc2[n][j]; }
                else {
                  if (drun >= 0) atomicAdd(&accU[drun*HH + h], vrun);
                  drun = dj[j]; vrun = acc2[n][j];
                }
              }
              if (drun >= 0) atomicAdd(&accU[drun*HH + h], vrun);
            }
          } else {
            // ---- vec aggregation: stage vw, pipelined wave-uniform gather ----
            #pragma unroll
            for (int n = 0; n < 8; ++n)
              #pragma unroll
              for (int j = 0; j < 4; ++j)
                hb[((lg<<2) + j)*136 + n*16 + l15] = f2bf(acc2[n][j]);

            const int nvalid = pend - tb;            // >= 1
            int myp = tb + l15;
            if (myp >= pend) myp = pend - 1;
            const int eidS = csr[myp];
            const int dstS = destp[myp] - i0;
            const int colS = colidx[eidS];
            const float dxS = dir[(size_t)eidS*3 + 0];
            const float dyS = dir[(size_t)eidS*3 + 1];
            const float dzS = dir[(size_t)eidS*3 + 2];
            const int ch = lane << 1;

            int drun = -1;
            float v00=0.f,v01=0.f,v10=0.f,v11=0.f,v20=0.f,v21=0.f;
            #pragma unroll
            for (int r = 0; r < 16; ++r){
              const int c  = __shfl(colS, r);        // readlane -> SGPR
              const int di = __shfl(dstS, r);
              const float d0 = __shfl(dxS, r);
              const float d1 = __shfl(dyS, r);
              const float d2 = __shfl(dzS, r);
              const unsigned short* fb = force_bf + (size_t)c*3*HH + ch;
              const unsigned int f0 = *(const unsigned int*)(fb);
              const unsigned int f1 = *(const unsigned int*)(fb + HH);
              const unsigned int f2 = *(const unsigned int*)(fb + 2*HH);
              const unsigned int vw2 = *(const unsigned int*)&hb[r*136 + ch];
              const bool valid = (r < nvalid);
              const float vl = valid ? bf2f(vw2 & 0xffffu) : 0.f;
              const float vh = valid ? bf2f(vw2 >> 16) : 0.f;
              if (di != drun){                       // wave-uniform scalar branch
                if (drun >= 0){
                  atomicAdd(&accU[(drun*3 + 0)*HH + ch],     v00);
                  atomicAdd(&accU[(drun*3 + 0)*HH + ch + 1], v01);
                  atomicAdd(&accU[(drun*3 + 1)*HH + ch],     v10);
                  atomicAdd(&accU[(drun*3 + 1)*HH + ch + 1], v11);
                  atomicAdd(&accU[(drun*3 + 2)*HH + ch],     v20);
                  atomicAdd(&accU[(drun*3 + 2)*HH + ch + 1], v21);
                }
                drun = di;
                v00=0.f; v01=0.f; v10=0.f; v11=0.f; v20=0.f; v21=0.f;
              }
              v00 = fmaf(vl, d0 + bf2f(f0 & 0xffffu), v00);
              v01 = fmaf(vh, d0 + bf2f(f0 >> 16),     v01);
              v10 = fmaf(vl, d1 + bf2f(f1 & 0xffffu), v10);
              v11 = fmaf(vh, d1 + bf2f(f1 >> 16),     v11);
              v20 = fmaf(vl, d2 + bf2f(f2 & 0xffffu), v20);
              v21 = fmaf(vh, d2 + bf2f(f2 >> 16),     v21);
            }
            if (drun >= 0){
              atomicAdd(&accU[(drun*3 + 0)*HH + ch],     v00);
              atomicAdd(&accU[(drun*3 + 0)*HH + ch + 1], v01);
              atomicAdd(&accU[(drun*3 + 1)*HH + ch],     v10);
              atomicAdd(&accU[(drun*3 + 1)*HH + ch + 1], v11);
              atomicAdd(&accU[(drun*3 + 2)*HH + ch],     v20);
              atomicAdd(&accU[(drun*3 + 2)*HH + ch + 1], v21);
            }
          }
        }
      }
      __syncthreads();
      // ---- write chunk aggregates (exclusive ownership, plain stores) ----
      if (pass == 0){
        const int tot = (i1 - i0)*HH;
        for (int idx = tid; idx < tot; idx += 512)
          scalar_agg[(size_t)i0*HH + idx] = accU[idx];
      } else {
        const int tot = (i1 - i0)*3*HH;
        for (int idx = tid; idx < tot; idx += 512)
          vec_agg[(size_t)i0*3*HH + idx] = accU[idx];
      }
      __syncthreads();
    }
  }
}

// ---------------- node / force MLP (256 -> 128 silu -> 128), bf16 MFMA ----------------
template<bool IS_FORCE>
__global__ __launch_bounds__(512, 2) void node_mlp_kernel(
    const float* __restrict__ X0,   // atom_node (N,128)
    const float* __restrict__ X1,
    const float* __restrict__ FRC,  // force flat (N,3,128)
    const float* __restrict__ W1, const float* __restrict__ b1,
    const float* __restrict__ W2, const float* __restrict__ b2,
    float* __restrict__ out, int M)
{
  __shared__ __align__(16) unsigned short sW1[128*264];   // [col][k], pad 256->264
  __shared__ __align__(16) unsigned short sW2[128*136];
  __shared__ __align__(16) unsigned short hbuf[8*16*136];

  const int tid = threadIdx.x;
  for (int idx = tid; idx < 256*128; idx += 512){
    int k = idx >> 7, c = idx & 127;
    sW1[c*264 + k] = f2bf(W1[idx]);
  }
  for (int idx = tid; idx < 128*128; idx += 512){
    int k = idx >> 7, c = idx & 127;
    sW2[c*136 + k] = f2bf(W2[idx]);
  }
  __syncthreads();

  const int w = tid >> 6, lane = tid & 63;
  const int l15 = lane & 15, lg = lane >> 4;
  unsigned short* hb = &hbuf[w*16*136];

  float b1v[8], b2v[8];
  #pragma unroll
  for (int n = 0; n < 8; ++n){ b1v[n] = b1[n*16 + l15]; b2v[n] = b2[n*16 + l15]; }

  const int ntiles = (M + 127) >> 7;
  for (int tile = blockIdx.x; tile < ntiles; tile += gridDim.x){
    const int m0 = (tile << 7) + (w << 4);
    int r = m0 + l15;
    int rr = (r < M) ? r : (M - 1);

    bf16x8 a[8];
    {
      const float* x0 = X0 + (size_t)(IS_FORCE ? (rr/3) : rr) * HH + lg*8;
      #pragma unroll
      for (int kt = 0; kt < 4; ++kt) a[kt] = pack8(x0 + kt*32);
    }
    if (IS_FORCE){
      const float* x1 = X1 + (size_t)rr * HH + lg*8;
      #pragma unroll
      for (int kt = 0; kt < 4; ++kt) a[kt+4] = pack8(x1 + kt*32);
    } else {
      #pragma unroll
      for (int kt = 0; kt < 4; ++kt){
        const float* sp = X1  + (size_t)rr*HH   + kt*32 + lg*8;
        const float* fp = FRC + (size_t)rr*3*HH + kt*32 + lg*8;
        bf16x8 tv;
        #pragma unroll
        for (int q = 0; q < 8; ++q){
          float f0 = fp[q], f1 = fp[q + HH], f2 = fp[q + 2*HH];
          tv[q] = (short)f2bf(sp[q] + f0*f0 + f1*f1 + f2*f2);
        }
        a[kt+4] = tv;
      }
    }

    f32x4 acc[8];
    #pragma unroll
    for (int n = 0; n < 8; ++n){ f32x4 t = {b1v[n],b1v[n],b1v[n],b1v[n]}; acc[n] = t; }
    #pragma unroll
    for (int kt = 0; kt < 8; ++kt){
      #pragma unroll
      for (int n = 0; n < 8; ++n){
        bf16x8 bf = *(const bf16x8*)&sW1[(n*16 + l15)*264 + kt*32 + lg*8];
        acc[n] = __builtin_amdgcn_mfma_f32_16x16x32_bf16(a[kt], bf, acc[n], 0, 0, 0);
      }
    }

    #pragma unroll
    for (int n = 0; n < 8; ++n)
      #pragma unroll
      for (int j = 0; j < 4; ++j)
        hb[((lg<<2) + j)*136 + n*16 + l15] = f2bf(silu_f(acc[n][j]));

    f32x4 acc2[8];
    #pragma unroll
    for (int n = 0; n < 8; ++n){ f32x4 t = {b2v[n],b2v[n],b2v[n],b2v[n]}; acc2[n] = t; }
    #pragma unroll
    for (int kt = 0; kt < 4; ++kt){
      bf16x8 a2 = *(const bf16x8*)&hb[l15*136 + kt*32 + lg*8];
      #pragma unroll
      for (int n = 0; n < 8; ++n){
        bf16x8 bf = *(const bf16x8*)&sW2[(n*16 + l15)*136 + kt*32 + lg*8];
        acc2[n] = __builtin_amdgcn_mfma_f32_16x16x32_bf16(a2, bf, acc2[n], 0, 0, 0);
      }
    }

    // epilogue: scattered f32 stores (64B-contiguous per 16-lane group)
    #pragma unroll
    for (int n = 0; n < 8; ++n){
      #pragma unroll
      for (int j = 0; j < 4; ++j){
        int R = m0 + (lg<<2) + j;
        if (R < M){
          size_t o = (size_t)R*HH + n*16 + l15;
          float y = acc2[n][j];
          float res;
          if (IS_FORCE){ float f = FRC[o]; res = f + y*f; }
          else         { res = X0[o] + y; }
          out[o] = res;
        }
      }
    }
  }
}

// ---------------- launch ----------------
extern "C" void kernel_launch(void* const* d_in, const int* in_sizes, int n_in,
                              void* d_out, int out_size, void* d_ws, size_t ws_size,
                              hipStream_t stream)
{
  const float* atom  = (const float*)d_in[0];
  const float* force = (const float*)d_in[1];
  const float* dir   = (const float*)d_in[2];
  const float* dist  = (const float*)d_in[3];
  const int*   eidx  = (const int*)d_in[4];
  const float* Wm1 = (const float*)d_in[5];  const float* bm1 = (const float*)d_in[6];
  const float* Wm2 = (const float*)d_in[7];  const float* bm2 = (const float*)d_in[8];
  const float* Wv1 = (const float*)d_in[9];  const float* bv1 = (const float*)d_in[10];
  const float* Wv2 = (const float*)d_in[11]; const float* bv2 = (const float*)d_in[12];
  const float* Wn1 = (const float*)d_in[13]; const float* bn1 = (const float*)d_in[14];
  const float* Wn2 = (const float*)d_in[15]; const float* bn2 = (const float*)d_in[16];
  const float* Wf1 = (const float*)d_in[17]; const float* bf1 = (const float*)d_in[18];
  const float* Wf2 = (const float*)d_in[19]; const float* bf2 = (const float*)d_in[20];

  const int N = in_sizes[0] / HH;
  const int E = in_sizes[2] / 3;
  const int* rowi = eidx;
  const int* coli = eidx + E;

  // workspace: CSR (~5.3 MB) + bf16 atom/force copies (~20.5 MB)
  char* ws = (char*)d_ws;
  size_t off = 0;
  auto take = [&](size_t bytes) -> void* {
    void* p = (void*)(ws + off);
    off += (bytes + 255) & ~(size_t)255;
    return p;
  };
  int* deg      = (int*)take((size_t)(N+1)*4);
  int* rowstart = (int*)take((size_t)(N+1)*4);
  int* cursor   = (int*)take((size_t)N*4);
  int* csr      = (int*)take((size_t)E*4);
  int* destp    = (int*)take((size_t)E*4);
  unsigned short* atom_bf  = (unsigned short*)take((size_t)N*HH*2);
  unsigned short* force_bf = (unsigned short*)take((size_t)N*3*HH*2);
  if (off > ws_size) return;  // degrade to wrong answer, not a page fault
  (void)n_in; (void)out_size;

  // aggregates alias d_out (fully overwritten by the MLP kernels afterwards)
  float* out0 = (float*)d_out;                    // scalar_agg -> atom_node_new
  float* out1 = out0 + (size_t)N*HH;              // vec_agg   -> force_node_new

  zero_kernel<<<(N+256)/256, 256, 0, stream>>>(deg, N+1);
  hist_kernel<<<(E+255)/256, 256, 0, stream>>>(rowi, deg, E);
  scan_kernel<<<1, 1024, 0, stream>>>(deg, rowstart, cursor, N);
  scatter_kernel<<<(E+255)/256, 256, 0, stream>>>(rowi, cursor, csr, destp, E);

  const int na4 = N*HH/4, nf4 = N*3*HH/4;
  tobf_kernel<<<(na4+255)/256, 256, 0, stream>>>(atom,  atom_bf,  na4);
  tobf_kernel<<<(nf4+255)/256, 256, 0, stream>>>(force, force_bf, nf4);

  const int nchunks = (N + 7) >> 3;
  int fgrid = nchunks < 256 ? nchunks : 256;
  fused_edge_kernel<<<fgrid, 512, 0, stream>>>(atom_bf, force_bf, dir, dist, coli,
      rowstart, csr, destp,
      Wm1,bm1,Wm2,bm2, Wv1,bv1,Wv2,bv2,
      out0, out1, N, nchunks);

  int nt_node  = (N + 127) >> 7;
  int nt_force = (3*N + 127) >> 7;
  node_mlp_kernel<false><<<nt_node, 512, 0, stream>>>(atom, out0, force,
      Wn1,bn1,Wn2,bn2, out0, N);
  node_mlp_kernel<true><<<nt_force, 512, 0, stream>>>(atom, out1, force,
      Wf1,bf1,Wf2,bf2, out1, 3*N);
}